// Round 4
// baseline (356.345 us; speedup 1.0000x reference)
//
#include <hip/hip_runtime.h>

typedef unsigned short u16;
typedef unsigned int   u32;
typedef __bf16  bf16x8 __attribute__((ext_vector_type(8)));
typedef float   f32x16 __attribute__((ext_vector_type(16)));

#define CAP      16384
#define L0_ELS   (256*48)                 // W_in^T image: 4 quarters x (6 chunks x 64 rows x 8)
#define HID_ELS  65536                    // 256x256, 4 quarters x (32 chunks x 64 rows x 8)
#define OUT_ELS  8192                     // 32 chunks x 32 rows x 8
#define HEAD_WS  (L0_ELS + 3*HID_ELS + OUT_ELS)   // 217088 bf16 elements per head
#define HID_OFF  L0_ELS
#define OUT_OFF  (L0_ELS + 3*HID_ELS)

union F8 { u32 u[4]; bf16x8 v; };

__device__ __forceinline__ u16 f2b(float f) {   // fp32 -> bf16 RTNE
  u32 u = __float_as_uint(f); u += 0x7fffu + ((u >> 16) & 1u); return (u16)(u >> 16);
}
__device__ __forceinline__ u32 packbf2(float a, float b) {
  u32 ua = __float_as_uint(a); ua += 0x7fffu + ((ua >> 16) & 1u);
  u32 ub = __float_as_uint(b); ub += 0x7fffu + ((ub >> 16) & 1u);
  return (ua >> 16) | (ub & 0xffff0000u);
}
__device__ __forceinline__ f32x16 mfma16(bf16x8 a, bf16x8 b, f32x16 c) {
  return __builtin_amdgcn_mfma_f32_32x32x16_bf16(a, b, c, 0, 0, 0);
}

// ---- staging for 256 threads: uint4 ld -> regs -> ds_write_b128 ----
__device__ __forceinline__ void stage_now(const u16* g, short* l, int bytes, int tid) {
  for (int base = tid * 16; base < bytes; base += 4096)
    *(uint4*)((char*)l + base) = *(const uint4*)((const char*)g + base);
}
__device__ __forceinline__ void stage_ld(const u16* g, int bytes, int tid, uint4 st[8]) {
#pragma unroll
  for (int r = 0; r < 8; ++r) {
    const int base = tid * 16 + r * 4096;
    if (base < bytes) st[r] = *(const uint4*)((const char*)g + base);
  }
}
__device__ __forceinline__ void stage_st(short* l, int bytes, int tid, const uint4 st[8]) {
#pragma unroll
  for (int r = 0; r < 8; ++r) {
    const int base = tid * 16 + r * 4096;
    if (base < bytes) *(uint4*)((char*)l + base) = st[r];
  }
}

// A-fragment readers, chunk-major conflict-free: addr = ((c*64) + 32*i + n) * 16, c = 2t+hh
__device__ __forceinline__ bf16x8 frag64(const short* sl, int i, int t, int n, int hh) {
  return *(const bf16x8*)((const char*)sl + ((((2*t + hh) << 6) + 32*i + n) << 4));
}
__device__ __forceinline__ bf16x8 fragO(const short* sl, int t, int n, int hh) {
  return *(const bf16x8*)((const char*)sl + ((((2*t + hh) << 5) + n) << 4));
}

// D(f32x16 C-layout) -> relu -> bf16 -> B-layout tiles 2r,2r+1 via lane^32 exchange
__device__ __forceinline__ void epi_core(const float cb[16], int hh, F8& t0, F8& t1) {
  u32 P[8];
#pragma unroll
  for (int i = 0; i < 8; ++i)
    P[i] = packbf2(fmaxf(cb[2*i], 0.f), fmaxf(cb[2*i+1], 0.f));
  u32 s0 = hh ? P[0] : P[2], s1 = hh ? P[1] : P[3];
  u32 s2 = hh ? P[4] : P[6], s3 = hh ? P[5] : P[7];
  u32 x0 = __shfl_xor(s0, 32, 64), x1 = __shfl_xor(s1, 32, 64);
  u32 x2 = __shfl_xor(s2, 32, 64), x3 = __shfl_xor(s3, 32, 64);
  t0.u[0] = hh ? x0 : P[0]; t0.u[1] = hh ? x1 : P[1];
  t0.u[2] = hh ? P[2] : x0; t0.u[3] = hh ? P[3] : x1;
  t1.u[0] = hh ? x2 : P[4]; t1.u[1] = hh ? x3 : P[5];
  t1.u[2] = hh ? P[6] : x2; t1.u[3] = hh ? P[7] : x3;
}
__device__ __forceinline__ void epilogue(f32x16 c, int hh, F8& t0, F8& t1) {
  float cb[16];
#pragma unroll
  for (int e = 0; e < 16; ++e) cb[e] = c[e];
  epi_core(cb, hh, t0, t1);
}
__device__ __forceinline__ void epilogueB(f32x16 c, const float4 bb[4], int hh, F8& t0, F8& t1) {
  float cb[16];
#pragma unroll
  for (int e = 0; e < 16; ++e) cb[e] = c[e] + ((const float*)bb)[e];
  epi_core(cb, hh, t0, t1);
}

// ---------------- prep_hid: LDS-transpose fp32 W_hid -> bf16 chunk-major images ----------------
// grid: 16 heads x 3 layers x 4 quarters x 4 kbands = 768 blocks x 256 thr
__global__ void prep_hid(const float* __restrict__ W_hid, u16* __restrict__ ws) {
  __shared__ u16 tile[64 * 72];                        // [k_local][row], padded
  const int b = blockIdx.x;
  const int kband = b & 3, q = (b >> 2) & 3, l = (b >> 4) % 3, head = b / 48;
  const int t = threadIdx.x;
  const int kl = t >> 2, rg = t & 3;                   // 4 threads per k-row, 16 rows each
  const float* src = W_hid + (((head*3 + l)*256 + kband*64 + kl) << 8) + q*64 + rg*16;
  u16* dt = &tile[kl*72 + rg*16];
#pragma unroll
  for (int m = 0; m < 4; ++m) {
    float4 v = *(const float4*)(src + m*4);
    ushort4 o; o.x = f2b(v.x); o.y = f2b(v.y); o.z = f2b(v.z); o.w = f2b(v.w);
    *(ushort4*)(dt + m*4) = o;
  }
  __syncthreads();
  u16* dbase = ws + head*HEAD_WS + HID_OFF + l*HID_ELS + q*16384 + (kband << 12);
#pragma unroll
  for (int p = 0; p < 2; ++p) {
    const int idx = t + p*256;                          // [0,512): cl = idx>>6, rq = idx&63
    const int cl = idx >> 6, rq = idx & 63;
    u16 v8[8];
#pragma unroll
    for (int j = 0; j < 8; ++j) v8[j] = tile[(cl*8 + j)*72 + rq];
    uint4 o;
    o.x = (u32)v8[0] | ((u32)v8[1] << 16); o.y = (u32)v8[2] | ((u32)v8[3] << 16);
    o.z = (u32)v8[4] | ((u32)v8[5] << 16); o.w = (u32)v8[6] | ((u32)v8[7] << 16);
    *(uint4*)(dbase + ((cl << 6) + rq) * 8) = o;        // chunk-major: (c*64 + row)*8
  }
}

// ---------------- prep_small: L0 (bias folded) + OUT images ----------------
// 16 heads x 2560 chunks = 40960 -> 160 blocks x 256 thr
__global__ void prep_small(const float* __restrict__ W_in, const float* __restrict__ b_in,
                           const float* __restrict__ W_out, u16* __restrict__ ws) {
  const int r = blockIdx.x * 256 + threadIdx.x;
  const int head = r / 2560, f = r % 2560;
  u16 v[8]; int dst;
  if (f < 1536) {                                       // L0: quarter q, chunk c (0..5), row
    const int q = f / 384, g = f % 384;
    const int c = g >> 6, row = g & 63, nn = q*64 + row, k0 = c*8;
#pragma unroll
    for (int j = 0; j < 8; ++j) {
      const int k = k0 + j;
      v[j] = (k < 40) ? f2b(W_in[head*10240 + (k << 8) + nn])
           : (k == 40) ? f2b(b_in[(head << 8) + nn]) : (u16)0;
    }
    dst = head*HEAD_WS + q*3072 + g*8;
  } else {                                              // OUT: 32 chunks x 32 rows
    const int f2 = f - 1536;
    const int c = f2 >> 5, nn = f2 & 31, k0 = c*8;
#pragma unroll
    for (int j = 0; j < 8; ++j)
      v[j] = (nn < 3) ? f2b(W_out[head*768 + (k0 + j)*3 + nn]) : (u16)0;
    dst = head*HEAD_WS + OUT_OFF + f2*8;
  }
  uint4 o;
  o.x = (u32)v[0] | ((u32)v[1] << 16); o.y = (u32)v[2] | ((u32)v[3] << 16);
  o.z = (u32)v[4] | ((u32)v[5] << 16); o.w = (u32)v[6] | ((u32)v[7] << 16);
  *(uint4*)(ws + dst) = o;
}

__global__ void copy_coords(const uint4* __restrict__ s, uint4* __restrict__ d) {
  const int i = blockIdx.x * 256 + threadIdx.x;
  d[i] = s[i];
}

// ---------------- main fused MLP: 256 thr (4 waves), 64 points/wave ----------------
__launch_bounds__(256, 1)
__global__ void mlp_main(const float* __restrict__ coords, const int* __restrict__ head_idx,
                         const float* __restrict__ b_hid, const float* __restrict__ b_out,
                         const u16* __restrict__ ws, float* __restrict__ out) {
  __shared__ short ring[2 * 16384];                    // 2 x 32 KB weight-quarter slots
  const int tid = threadIdx.x;
  const int lane = tid & 63, wv = tid >> 6;
  const int n = lane & 31, hh = lane >> 5;
  const int head = blockIdx.x & 15, chunk = blockIdx.x >> 4;
  const u16* wsh = ws + head * HEAD_WS;

  stage_now(wsh + 0*3072, ring,          6144, tid);   // L0 q0 -> slot0
  stage_now(wsh + 1*3072, ring + 16384,  6144, tid);   // L0 q1 -> slot1

  // two point-groups per wave
  const int ptA = chunk*256 + wv*64 + n, ptB = ptA + 32;
  const int gA = head_idx[head*CAP + ptA];
  const int gB = head_idx[head*CAP + ptB];
  const float2 cA = *(const float2*)(coords + 2*gA);
  const float2 cB = *(const float2*)(coords + 2*gB);
  const float bo0 = b_out[head*3+0], bo1 = b_out[head*3+1], bo2 = b_out[head*3+2];

  F8 peA[3], peB[3];
#pragma unroll
  for (int grp = 0; grp < 2; ++grp) {
    const float xs = grp ? cB.x : cA.x, ys = grp ? cB.y : cA.y;
    F8* pe = grp ? peB : peA;
#pragma unroll
    for (int t = 0; t < 3; ++t) {
      float e[8];
#pragma unroll
      for (int half = 0; half < 2; ++half) {
        const int l = 4*t + 2*hh + half;               // k = 4l + comp: sinx,siny,cosx,cosy
        if (l < 10) {
          const float fr = 3.14159265358979323846f * (float)(1 << l);
          float s1, c1, s2, c2;
          sincosf(xs * fr, &s1, &c1);
          sincosf(ys * fr, &s2, &c2);
          e[4*half+0] = s1; e[4*half+1] = s2; e[4*half+2] = c1; e[4*half+3] = c2;
        } else {
          e[4*half+0] = (l == 10) ? 1.0f : 0.0f;       // k=40 -> folded bias channel
          e[4*half+1] = 0.f; e[4*half+2] = 0.f; e[4*half+3] = 0.f;
        }
      }
      pe[t].u[0] = packbf2(e[0], e[1]); pe[t].u[1] = packbf2(e[2], e[3]);
      pe[t].u[2] = packbf2(e[4], e[5]); pe[t].u[3] = packbf2(e[6], e[7]);
    }
  }

  F8 actA0[16], actA1[16], actB0[16], actB1[16];
  __syncthreads();

  // ===== layer 0: pe -> act*0 (K=48, bias folded) =====
#pragma unroll
  for (int rp = 0; rp < 4; ++rp) {
    short* sl = ring + (rp & 1) * 16384;
    f32x16 aA0 = (f32x16)0.f, aA1 = (f32x16)0.f, aB0 = (f32x16)0.f, aB1 = (f32x16)0.f;
#pragma unroll
    for (int t = 0; t < 3; ++t) {
      bf16x8 f0 = frag64(sl, 0, t, n, hh);
      bf16x8 f1 = frag64(sl, 1, t, n, hh);
      aA0 = mfma16(f0, peA[t].v, aA0); aB0 = mfma16(f0, peB[t].v, aB0);
      aA1 = mfma16(f1, peA[t].v, aA1); aB1 = mfma16(f1, peB[t].v, aB1);
    }
    __syncthreads();
    const u16* src = (rp < 2) ? (wsh + (rp + 2)*3072) : (wsh + HID_OFF + (rp - 2)*16384);
    const int bytes = (rp < 2) ? 6144 : 32768;
    uint4 st[8];
    stage_ld(src, bytes, tid, st);
    epilogue(aA0, hh, actA0[4*rp+0], actA0[4*rp+1]);
    epilogue(aA1, hh, actA0[4*rp+2], actA0[4*rp+3]);
    epilogue(aB0, hh, actB0[4*rp+0], actB0[4*rp+1]);
    epilogue(aB1, hh, actB0[4*rp+2], actB0[4*rp+3]);
    stage_st(sl, bytes, tid, st);
  }

  // ===== hidden layers =====
  auto hid_layer = [&](const float* bias, F8 (&ainA)[16], F8 (&ainB)[16],
                       F8 (&aoutA)[16], F8 (&aoutB)[16],
                       const u16* j0, const u16* j1, const u16* j2, const u16* j3,
                       int b2, int b3) {
    const u16* jsrc[4] = { j0, j1, j2, j3 };
    const int  jb[4]   = { 32768, 32768, b2, b3 };
#pragma unroll
    for (int rp = 0; rp < 4; ++rp) {
      short* sl = ring + (rp & 1) * 16384;
      f32x16 aA0 = (f32x16)0.f, aA1 = (f32x16)0.f, aB0 = (f32x16)0.f, aB1 = (f32x16)0.f;
#pragma unroll
      for (int t = 0; t < 16; ++t) {
        bf16x8 f0 = frag64(sl, 0, t, n, hh);
        bf16x8 f1 = frag64(sl, 1, t, n, hh);
        aA0 = mfma16(f0, ainA[t].v, aA0); aB0 = mfma16(f0, ainB[t].v, aB0);
        aA1 = mfma16(f1, ainA[t].v, aA1); aB1 = mfma16(f1, ainB[t].v, aB1);
      }
      __syncthreads();
      uint4 st[8];
      if (jb[rp] > 0) stage_ld(jsrc[rp], jb[rp], tid, st);
      float4 bb0[4], bb1[4];                            // rows 64rp+32i+8g+4hh+[0..3]
#pragma unroll
      for (int g2 = 0; g2 < 4; ++g2) {
        bb0[g2] = *(const float4*)(bias + 64*rp +      8*g2 + 4*hh);
        bb1[g2] = *(const float4*)(bias + 64*rp + 32 + 8*g2 + 4*hh);
      }
      epilogueB(aA0, bb0, hh, aoutA[4*rp+0], aoutA[4*rp+1]);
      epilogueB(aA1, bb1, hh, aoutA[4*rp+2], aoutA[4*rp+3]);
      epilogueB(aB0, bb0, hh, aoutB[4*rp+0], aoutB[4*rp+1]);
      epilogueB(aB1, bb1, hh, aoutB[4*rp+2], aoutB[4*rp+3]);
      if (jb[rp] > 0) stage_st(sl, jb[rp], tid, st);
    }
  };

  const u16* hb = wsh + HID_OFF;
  hid_layer(b_hid + (head*3+0)*256, actA0, actB0, actA1, actB1,
            hb + 2*16384, hb + 3*16384, hb + HID_ELS, hb + HID_ELS + 16384, 32768, 32768);
  hid_layer(b_hid + (head*3+1)*256, actA1, actB1, actA0, actB0,
            hb + HID_ELS + 2*16384, hb + HID_ELS + 3*16384,
            hb + 2*HID_ELS, hb + 2*HID_ELS + 16384, 32768, 32768);
  hid_layer(b_hid + (head*3+2)*256, actA0, actB0, actA1, actB1,
            hb + 2*HID_ELS + 2*16384, hb + 2*HID_ELS + 3*16384,
            wsh + OUT_OFF, (const u16*)0, 16384, 0);

  // ===== out layer: act*1 x W_out^T (32-row image in slot0), scatter =====
  f32x16 oA = (f32x16)0.f, oB = (f32x16)0.f;
#pragma unroll
  for (int t = 0; t < 16; ++t) {
    bf16x8 f = fragO(ring, t, n, hh);
    oA = mfma16(f, actA1[t].v, oA);
    oB = mfma16(f, actB1[t].v, oB);
  }
  if (hh == 0) {                                       // rows 0..2 live in hh=0 regs 0..2
    const long bA = (long)gA * 3, bB = (long)gB * 3;
    out[bA + 0] = oA[0] + bo0; out[bA + 1] = oA[1] + bo1; out[bA + 2] = oA[2] + bo2;
    out[bB + 0] = oB[0] + bo0; out[bB + 1] = oB[1] + bo1; out[bB + 2] = oB[2] + bo2;
  }
}

extern "C" void kernel_launch(void* const* d_in, const int* in_sizes, int n_in,
                              void* d_out, int out_size, void* d_ws, size_t ws_size,
                              hipStream_t stream) {
  const float* coords   = (const float*)d_in[0];
  const int*   head_idx = (const int*)d_in[1];
  const float* W_in     = (const float*)d_in[2];
  const float* b_in     = (const float*)d_in[3];
  const float* W_hid    = (const float*)d_in[4];
  const float* b_hid    = (const float*)d_in[5];
  const float* W_out    = (const float*)d_in[6];
  const float* b_out    = (const float*)d_in[7];
  float* out = (float*)d_out;
  u16*   ws  = (u16*)d_ws;
  if (ws_size < (size_t)HEAD_WS * 16 * sizeof(u16)) return;

  prep_hid  <<<dim3(768), dim3(256), 0, stream>>>(W_hid, ws);
  prep_small<<<dim3(160), dim3(256), 0, stream>>>(W_in, b_in, W_out, ws);
  copy_coords<<<dim3(512), dim3(256), 0, stream>>>((const uint4*)coords, (uint4*)(out + 786432));
  mlp_main  <<<dim3(1024), dim3(256), 0, stream>>>(coords, head_idx, b_hid, b_out, ws, out);
}

// Round 5
// 233.023 us; speedup vs baseline: 1.5292x; 1.5292x over previous
//
#include <hip/hip_runtime.h>

typedef unsigned short u16;
typedef unsigned int   u32;
typedef __bf16  bf16x8 __attribute__((ext_vector_type(8)));
typedef float   f32x16 __attribute__((ext_vector_type(16)));

#define CAP      16384
#define L0_ELS   (256*48)                 // W_in^T image: 4 quarters x (6 chunks x 64 rows x 8)
#define HID_ELS  65536                    // 256x256: 4 quarters x (32 chunks x 64 rows x 8)
#define OUT_ELS  8192                     // 32 chunks x 32 rows x 8
#define HEAD_WS  (L0_ELS + 3*HID_ELS + OUT_ELS)   // 217088 bf16 elements per head
#define HID_OFF  L0_ELS
#define OUT_OFF  (L0_ELS + 3*HID_ELS)

union F8 { u32 u[4]; bf16x8 v; };

__device__ __forceinline__ u16 f2b(float f) {   // fp32 -> bf16 RTNE
  u32 u = __float_as_uint(f); u += 0x7fffu + ((u >> 16) & 1u); return (u16)(u >> 16);
}
__device__ __forceinline__ u32 packbf2(float a, float b) {
  u32 ua = __float_as_uint(a); ua += 0x7fffu + ((ua >> 16) & 1u);
  u32 ub = __float_as_uint(b); ub += 0x7fffu + ((ub >> 16) & 1u);
  return (ua >> 16) | (ub & 0xffff0000u);
}
__device__ __forceinline__ f32x16 mfma16(bf16x8 a, bf16x8 b, f32x16 c) {
  return __builtin_amdgcn_mfma_f32_32x32x16_bf16(a, b, c, 0, 0, 0);
}

// ---- staging for 512 threads: uint4 ld -> regs -> ds_write_b128 ----
__device__ __forceinline__ void stage_now(const u16* g, short* l, int bytes, int tid) {
  for (int base = tid * 16; base < bytes; base += 8192)
    *(uint4*)((char*)l + base) = *(const uint4*)((const char*)g + base);
}
__device__ __forceinline__ void stage_ld(const u16* g, int bytes, int tid, uint4 st[4]) {
#pragma unroll
  for (int r = 0; r < 4; ++r) {
    const int base = tid * 16 + r * 8192;
    if (base < bytes) st[r] = *(const uint4*)((const char*)g + base);
  }
}
__device__ __forceinline__ void stage_st(short* l, int bytes, int tid, const uint4 st[4]) {
#pragma unroll
  for (int r = 0; r < 4; ++r) {
    const int base = tid * 16 + r * 8192;
    if (base < bytes) *(uint4*)((char*)l + base) = st[r];
  }
}

// A-fragment readers, chunk-major conflict-free (R4-verified: SQ_LDS_BANK_CONFLICT=0):
// addr = ((c*64) + 32*i + n) * 16, c = 2t+hh
__device__ __forceinline__ bf16x8 frag64(const short* sl, int i, int t, int n, int hh) {
  return *(const bf16x8*)((const char*)sl + ((((2*t + hh) << 6) + 32*i + n) << 4));
}
__device__ __forceinline__ bf16x8 fragO(const short* sl, int t, int n, int hh) {
  return *(const bf16x8*)((const char*)sl + ((((2*t + hh) << 5) + n) << 4));
}

// D(f32x16 C-layout) -> (+bias) -> relu -> bf16 -> B-layout tiles 2r,2r+1 via lane^32 exchange
__device__ __forceinline__ void epi_core(const float cb[16], int hh, F8& t0, F8& t1) {
  u32 P[8];
#pragma unroll
  for (int i = 0; i < 8; ++i)
    P[i] = packbf2(fmaxf(cb[2*i], 0.f), fmaxf(cb[2*i+1], 0.f));
  u32 s0 = hh ? P[0] : P[2], s1 = hh ? P[1] : P[3];
  u32 s2 = hh ? P[4] : P[6], s3 = hh ? P[5] : P[7];
  u32 x0 = __shfl_xor(s0, 32, 64), x1 = __shfl_xor(s1, 32, 64);
  u32 x2 = __shfl_xor(s2, 32, 64), x3 = __shfl_xor(s3, 32, 64);
  t0.u[0] = hh ? x0 : P[0]; t0.u[1] = hh ? x1 : P[1];
  t0.u[2] = hh ? P[2] : x0; t0.u[3] = hh ? P[3] : x1;
  t1.u[0] = hh ? x2 : P[4]; t1.u[1] = hh ? x3 : P[5];
  t1.u[2] = hh ? P[6] : x2; t1.u[3] = hh ? P[7] : x3;
}
__device__ __forceinline__ void epilogue(f32x16 c, int hh, F8& t0, F8& t1) {
  float cb[16];
#pragma unroll
  for (int e = 0; e < 16; ++e) cb[e] = c[e];
  epi_core(cb, hh, t0, t1);
}
__device__ __forceinline__ void epilogueB(f32x16 c, const float4 bb[4], int hh, F8& t0, F8& t1) {
  float cb[16];
#pragma unroll
  for (int e = 0; e < 16; ++e) cb[e] = c[e] + ((const float*)bb)[e];
  epi_core(cb, hh, t0, t1);
}

// ---------------- prep_hid: LDS-transpose fp32 W_hid -> bf16 chunk-major images ----------------
// grid: 16 heads x 3 layers x 4 quarters x 4 kbands = 768 blocks x 256 thr (R4-verified)
__global__ void prep_hid(const float* __restrict__ W_hid, u16* __restrict__ ws) {
  __shared__ u16 tile[64 * 72];                        // [k_local][row], padded
  const int b = blockIdx.x;
  const int kband = b & 3, q = (b >> 2) & 3, l = (b >> 4) % 3, head = b / 48;
  const int t = threadIdx.x;
  const int kl = t >> 2, rg = t & 3;                   // 4 threads per k-row, 16 rows each
  const float* src = W_hid + (((head*3 + l)*256 + kband*64 + kl) << 8) + q*64 + rg*16;
  u16* dt = &tile[kl*72 + rg*16];
#pragma unroll
  for (int m = 0; m < 4; ++m) {
    float4 v = *(const float4*)(src + m*4);
    ushort4 o; o.x = f2b(v.x); o.y = f2b(v.y); o.z = f2b(v.z); o.w = f2b(v.w);
    *(ushort4*)(dt + m*4) = o;
  }
  __syncthreads();
  u16* dbase = ws + head*HEAD_WS + HID_OFF + l*HID_ELS + q*16384 + (kband << 12);
#pragma unroll
  for (int p = 0; p < 2; ++p) {
    const int idx = t + p*256;                          // [0,512): cl = idx>>6, rq = idx&63
    const int cl = idx >> 6, rq = idx & 63;
    u16 v8[8];
#pragma unroll
    for (int j = 0; j < 8; ++j) v8[j] = tile[(cl*8 + j)*72 + rq];
    uint4 o;
    o.x = (u32)v8[0] | ((u32)v8[1] << 16); o.y = (u32)v8[2] | ((u32)v8[3] << 16);
    o.z = (u32)v8[4] | ((u32)v8[5] << 16); o.w = (u32)v8[6] | ((u32)v8[7] << 16);
    *(uint4*)(dbase + ((cl << 6) + rq) * 8) = o;        // chunk-major: (c*64 + row)*8
  }
}

// ---------------- prep_small: L0 (bias folded) + OUT images, + coords passthrough ----------------
// blocks [0,160): weight images; blocks [160,672): coords copy (one fewer launch)
__global__ void prep_small(const float* __restrict__ W_in, const float* __restrict__ b_in,
                           const float* __restrict__ W_out, u16* __restrict__ ws,
                           const uint4* __restrict__ csrc, uint4* __restrict__ cdst) {
  if (blockIdx.x >= 160) {
    const int i = (blockIdx.x - 160) * 256 + threadIdx.x;   // 512 x 256 = 131072 uint4
    cdst[i] = csrc[i];
    return;
  }
  const int r = blockIdx.x * 256 + threadIdx.x;
  const int head = r / 2560, f = r % 2560;
  u16 v[8]; int dst;
  if (f < 1536) {                                       // L0: quarter q, chunk c (0..5), row
    const int q = f / 384, g = f % 384;
    const int c = g >> 6, row = g & 63, nn = q*64 + row, k0 = c*8;
#pragma unroll
    for (int j = 0; j < 8; ++j) {
      const int k = k0 + j;
      v[j] = (k < 40) ? f2b(W_in[head*10240 + (k << 8) + nn])
           : (k == 40) ? f2b(b_in[(head << 8) + nn]) : (u16)0;
    }
    dst = head*HEAD_WS + q*3072 + g*8;
  } else {                                              // OUT: 32 chunks x 32 rows
    const int f2 = f - 1536;
    const int c = f2 >> 5, nn = f2 & 31, k0 = c*8;
#pragma unroll
    for (int j = 0; j < 8; ++j)
      v[j] = (nn < 3) ? f2b(W_out[head*768 + (k0 + j)*3 + nn]) : (u16)0;
    dst = head*HEAD_WS + OUT_OFF + f2*8;
  }
  uint4 o;
  o.x = (u32)v[0] | ((u32)v[1] << 16); o.y = (u32)v[2] | ((u32)v[3] << 16);
  o.z = (u32)v[4] | ((u32)v[5] << 16); o.w = (u32)v[6] | ((u32)v[7] << 16);
  *(uint4*)(ws + dst) = o;
}

// ---------------- main fused MLP: 512 thr (8 waves), 32 points/wave ----------------
__launch_bounds__(512, 2)
__global__ void mlp_main(const float* __restrict__ coords, const int* __restrict__ head_idx,
                         const float* __restrict__ b_hid, const float* __restrict__ b_out,
                         const u16* __restrict__ ws, float* __restrict__ out) {
  __shared__ short ring[2 * 16384];                    // 2 x 32 KB weight-quarter slots
  const int tid = threadIdx.x;
  const int lane = tid & 63, wv = tid >> 6;
  const int n = lane & 31, hh = lane >> 5;
  const int head = blockIdx.x & 15, chunk = blockIdx.x >> 4;   // head -> fixed XCD (L2 locality)
  const u16* wsh = ws + head * HEAD_WS;

  stage_now(wsh + 0*3072, ring,          6144, tid);   // L0 q0 -> slot0
  stage_now(wsh + 1*3072, ring + 16384,  6144, tid);   // L0 q1 -> slot1

  // gather + positional encoding (B-layout: lane = point, k = 16t + 8*hh + j)
  const int pt = chunk*256 + wv*32 + n;
  const int g  = head_idx[head*CAP + pt];
  const float2 cxy = *(const float2*)(coords + 2*g);
  const float xs = cxy.x, ys = cxy.y;
  const float bo0 = b_out[head*3+0], bo1 = b_out[head*3+1], bo2 = b_out[head*3+2];

  F8 pe[3];
#pragma unroll
  for (int t = 0; t < 3; ++t) {
    float e[8];
#pragma unroll
    for (int half = 0; half < 2; ++half) {
      const int l = 4*t + 2*hh + half;                 // k = 4l + comp: sinx,siny,cosx,cosy
      if (l < 10) {
        const float fr = 3.14159265358979323846f * (float)(1 << l);
        float s1, c1, s2, c2;
        sincosf(xs * fr, &s1, &c1);
        sincosf(ys * fr, &s2, &c2);
        e[4*half+0] = s1; e[4*half+1] = s2; e[4*half+2] = c1; e[4*half+3] = c2;
      } else {
        e[4*half+0] = (l == 10) ? 1.0f : 0.0f;         // k=40 -> folded bias channel
        e[4*half+1] = 0.f; e[4*half+2] = 0.f; e[4*half+3] = 0.f;
      }
    }
    pe[t].u[0] = packbf2(e[0], e[1]); pe[t].u[1] = packbf2(e[2], e[3]);
    pe[t].u[2] = packbf2(e[4], e[5]); pe[t].u[3] = packbf2(e[6], e[7]);
  }

  F8 act0[16], act1[16];
  __syncthreads();                                     // L0 q0/q1 staged

  // ===== layer 0: pe -> act0 (K=48, bias folded) =====
#pragma unroll
  for (int rp = 0; rp < 4; ++rp) {
    short* sl = ring + (rp & 1) * 16384;
    f32x16 acc0 = (f32x16)0.f, acc1 = (f32x16)0.f;
#pragma unroll
    for (int t = 0; t < 3; ++t) {
      acc0 = mfma16(frag64(sl, 0, t, n, hh), pe[t].v, acc0);
      acc1 = mfma16(frag64(sl, 1, t, n, hh), pe[t].v, acc1);
    }
    __syncthreads();
    const u16* src = (rp < 2) ? (wsh + (rp + 2)*3072) : (wsh + HID_OFF + (rp - 2)*16384);
    const int bytes = (rp < 2) ? 6144 : 32768;
    uint4 st[4];
    stage_ld(src, bytes, tid, st);                     // issue loads early
    epilogue(acc0, hh, act0[4*rp+0], act0[4*rp+1]);
    epilogue(acc1, hh, act0[4*rp+2], act0[4*rp+3]);
    stage_st(sl, bytes, tid, st);                      // drained by next barrier
  }

  // ===== hidden layers =====
  auto hid_layer = [&](const float* bias, F8 (&ain)[16], F8 (&aout)[16],
                       const u16* j0, const u16* j1, const u16* j2, const u16* j3,
                       int b2, int b3) {
    const u16* jsrc[4] = { j0, j1, j2, j3 };
    const int  jb[4]   = { 32768, 32768, b2, b3 };
#pragma unroll
    for (int rp = 0; rp < 4; ++rp) {
      short* sl = ring + (rp & 1) * 16384;
      f32x16 acc0 = (f32x16)0.f, acc1 = (f32x16)0.f;
#pragma unroll
      for (int t = 0; t < 16; ++t) {
        acc0 = mfma16(frag64(sl, 0, t, n, hh), ain[t].v, acc0);
        acc1 = mfma16(frag64(sl, 1, t, n, hh), ain[t].v, acc1);
      }
      __syncthreads();
      uint4 st[4];
      if (jb[rp] > 0) stage_ld(jsrc[rp], jb[rp], tid, st);
      float4 bb0[4], bb1[4];                            // rows 64rp+32i+8g+4hh+[0..3]
#pragma unroll
      for (int g2 = 0; g2 < 4; ++g2) {
        bb0[g2] = *(const float4*)(bias + 64*rp +      8*g2 + 4*hh);
        bb1[g2] = *(const float4*)(bias + 64*rp + 32 + 8*g2 + 4*hh);
      }
      epilogueB(acc0, bb0, hh, aout[4*rp+0], aout[4*rp+1]);
      epilogueB(acc1, bb1, hh, aout[4*rp+2], aout[4*rp+3]);
      if (jb[rp] > 0) stage_st(sl, jb[rp], tid, st);
    }
  };

  const u16* hb = wsh + HID_OFF;
  hid_layer(b_hid + (head*3+0)*256, act0, act1,
            hb + 2*16384, hb + 3*16384, hb + HID_ELS, hb + HID_ELS + 16384, 32768, 32768);
  hid_layer(b_hid + (head*3+1)*256, act1, act0,
            hb + HID_ELS + 2*16384, hb + HID_ELS + 3*16384,
            hb + 2*HID_ELS, hb + 2*HID_ELS + 16384, 32768, 32768);
  hid_layer(b_hid + (head*3+2)*256, act0, act1,
            hb + 2*HID_ELS + 2*16384, hb + 2*HID_ELS + 3*16384,
            wsh + OUT_OFF, (const u16*)0, 16384, 0);

  // ===== out layer: act1 x W_out^T (32-row image in slot0), scatter =====
  f32x16 acc = (f32x16)0.f;
#pragma unroll
  for (int t = 0; t < 16; ++t)
    acc = mfma16(fragO(ring, t, n, hh), act1[t].v, acc);
  if (hh == 0) {                                       // rows 0..2 live in hh=0 regs 0..2
    const long base = (long)g * 3;
    out[base + 0] = acc[0] + bo0;
    out[base + 1] = acc[1] + bo1;
    out[base + 2] = acc[2] + bo2;
  }
}

extern "C" void kernel_launch(void* const* d_in, const int* in_sizes, int n_in,
                              void* d_out, int out_size, void* d_ws, size_t ws_size,
                              hipStream_t stream) {
  const float* coords   = (const float*)d_in[0];
  const int*   head_idx = (const int*)d_in[1];
  const float* W_in     = (const float*)d_in[2];
  const float* b_in     = (const float*)d_in[3];
  const float* W_hid    = (const float*)d_in[4];
  const float* b_hid    = (const float*)d_in[5];
  const float* W_out    = (const float*)d_in[6];
  const float* b_out    = (const float*)d_in[7];
  float* out = (float*)d_out;
  u16*   ws  = (u16*)d_ws;
  if (ws_size < (size_t)HEAD_WS * 16 * sizeof(u16)) return;

  prep_hid  <<<dim3(768), dim3(256), 0, stream>>>(W_hid, ws);
  prep_small<<<dim3(672), dim3(256), 0, stream>>>(W_in, b_in, W_out, ws,
                                                  (const uint4*)coords, (uint4*)(out + 786432));
  mlp_main  <<<dim3(1024), dim3(512), 0, stream>>>(coords, head_idx, b_hid, b_out, ws, out);
}